// Round 1
// baseline (441681.641 us; speedup 1.0000x reference)
//
#include <hip/hip_runtime.h>
#include <hip/hip_cooperative_groups.h>
#include <math.h>

namespace cg = cooperative_groups;

#define H 1024
#define D 256
#define NB 256
#define NT 256

__device__ __forceinline__ float sigf(float v) { return 1.f / (1.f + __expf(-v)); }

__device__ __forceinline__ float waveReduce(float v) {
#pragma unroll
    for (int off = 32; off > 0; off >>= 1) v += __shfl_xor(v, off, 64);
    return v;
}

__global__ __launch_bounds__(NT) void rnn_persistent(
    const float* __restrict__ x, const float* __restrict__ h0, const float* __restrict__ c0,
    const float* __restrict__ Wih0, const float* __restrict__ Whh0,
    const float* __restrict__ Wih1, const float* __restrict__ Whh1,
    const float* __restrict__ Wih2, const float* __restrict__ Whh2,
    const float* __restrict__ b_ih, const float* __restrict__ b_hh,
    const float* __restrict__ Wfc, const float* __restrict__ bfc,
    float* __restrict__ out, float* __restrict__ ws,
    int T, int L)
{
    cg::grid_group grid = cg::this_grid();
    const int b = blockIdx.x;
    const int tid = threadIdx.x;
    const int w = tid >> 6;     // wave within block (0..3)
    const int lane = tid & 63;

    float* hb  = ws;                 // [2][3*H] double-buffered hidden states
    float* cs  = ws + 2 * 3 * H;     // [3*H] cell states (in-place: each unit owned by one wave)
    float* inp = ws + 2 * 3 * H + 3 * H; // [D] current input vector

    // ---- init (every call: harness poisons ws once, never restores) ----
    for (int i = b * NT + tid; i < 3 * H; i += NB * NT) { hb[i] = h0[i]; cs[i] = c0[i]; }
    for (int i = b * NT + tid; i < D; i += NB * NT) {
        float v = x[i * L];          // x[0, d, 0]
        inp[i] = v;
        out[(size_t)i * T] = v;      // out[:, t=0] = x_seq[0]
    }
    grid.sync();

    const float* WihA[3] = { Wih0, Wih1, Wih2 };
    const float* WhhA[3] = { Whh0, Whh1, Whh2 };

    const int u = b * 4 + w;         // hidden unit this wave owns (same for every layer)

    for (int s = 0; s < T - 1; ++s) {
        const int p = s & 1;
        const float* h_old = hb + p * 3 * H;        // states entering step s
        float*       h_new = hb + (p ^ 1) * 3 * H;  // states produced by step s

#pragma unroll
        for (int l = 0; l < 3; ++l) {
            const int KI = (l == 0) ? D : H;
            const float* Wih = WihA[l];
            const float* Whh = WhhA[l];
            const float* iv = (l == 0) ? inp : (h_new + (l - 1) * H); // feedforward input (new h of layer below)
            const float* hr = h_old + l * H;                          // recurrent input (old h of this layer)

            float g4[4];
#pragma unroll
            for (int g = 0; g < 4; ++g) {
                const int row = g * H + u;           // PyTorch gate order i,f,g,o
                float acc = 0.f;
                const float* wr = Wih + (size_t)row * KI;
                for (int k = lane; k < KI; k += 64) acc += wr[k] * iv[k];
                const float* wr2 = Whh + (size_t)row * H;
                for (int k = lane; k < H; k += 64) acc += wr2[k] * hr[k];
                acc = waveReduce(acc);
                g4[g] = acc + b_ih[l * 4 * H + row] + b_hh[l * 4 * H + row];
            }
            const float ig = sigf(g4[0]);
            const float fg = sigf(g4[1]);
            const float gg = tanhf(g4[2]);
            const float og = sigf(g4[3]);
            const float cn = fg * cs[l * H + u] + ig * gg;
            const float hn = og * tanhf(cn);
            if (lane == 0) {
                cs[l * H + u] = cn;
                h_new[l * H + u] = hn;
            }
            grid.sync();
        }

        // ---- fc / generation phase: row r = blockIdx, wave 0 only ----
        if (w == 0) {
            const int r = b;                         // 256 rows, 256 blocks
            float acc = 0.f;
            const float* wr = Wfc + (size_t)r * H;
            const float* h2 = h_new + 2 * H;
            for (int k = lane; k < H; k += 64) acc += wr[k] * h2[k];
            acc = waveReduce(acc);
            const float genv = sigf(acc + bfc[r]);
            const float nxt = ((s + 1) < L) ? x[r * L + (s + 1)] : genv;
            if (lane == 0) {
                inp[r] = nxt;                        // input for step s+1
                out[(size_t)r * T + (s + 1)] = nxt;  // out[:, s+1]
            }
        }
        grid.sync();
    }
}

extern "C" void kernel_launch(void* const* d_in, const int* in_sizes, int n_in,
                              void* d_out, int out_size, void* d_ws, size_t ws_size,
                              hipStream_t stream) {
    const float* x    = (const float*)d_in[0];
    const float* h0   = (const float*)d_in[1];
    const float* c0   = (const float*)d_in[2];
    const float* Wih0 = (const float*)d_in[3];
    const float* Whh0 = (const float*)d_in[4];
    const float* Wih1 = (const float*)d_in[5];
    const float* Whh1 = (const float*)d_in[6];
    const float* Wih2 = (const float*)d_in[7];
    const float* Whh2 = (const float*)d_in[8];
    const float* bih  = (const float*)d_in[9];
    const float* bhh  = (const float*)d_in[10];
    const float* Wfc  = (const float*)d_in[11];
    const float* bfc  = (const float*)d_in[12];

    float* out = (float*)d_out;
    float* ws  = (float*)d_ws;

    int T = out_size / D;        // 2048
    int L = in_sizes[0] / D;     // 64 warmup (teacher-forced) steps

    void* args[] = { &x, &h0, &c0, &Wih0, &Whh0, &Wih1, &Whh1, &Wih2, &Whh2,
                     &bih, &bhh, &Wfc, &bfc, &out, &ws, &T, &L };

    hipLaunchCooperativeKernel((void*)rnn_persistent, dim3(NB), dim3(NT), args, 0, stream);
}

// Round 2
// 227978.296 us; speedup vs baseline: 1.9374x; 1.9374x over previous
//
#include <hip/hip_runtime.h>
#include <hip/hip_cooperative_groups.h>
#include <math.h>

namespace cg = cooperative_groups;

#define H 1024
#define D 256
#define NB 256
#define NT 1024

__device__ __forceinline__ float sigf(float v) { return 1.f / (1.f + __expf(-v)); }

__device__ __forceinline__ float waveReduce(float v) {
#pragma unroll
    for (int off = 32; off > 0; off >>= 1) v += __shfl_xor(v, off, 64);
    return v;
}

__global__ __launch_bounds__(NT, 4) void rnn_reg(
    const float* __restrict__ x, const float* __restrict__ h0, const float* __restrict__ c0,
    const float* __restrict__ Wih0, const float* __restrict__ Whh0,
    const float* __restrict__ Wih1, const float* __restrict__ Whh1,
    const float* __restrict__ Wih2, const float* __restrict__ Whh2,
    const float* __restrict__ b_ih, const float* __restrict__ b_hh,
    const float* __restrict__ Wfc, const float* __restrict__ bfc,
    float* __restrict__ out, float* __restrict__ ws,
    int T, int L)
{
    cg::grid_group grid = cg::this_grid();
    const int b = blockIdx.x;
    const int tid = threadIdx.x;
    const int w = tid >> 6;        // wave 0..15
    const int lane = tid & 63;
    const int gate = w & 3;        // i,f,g,o
    const int ul = w >> 2;         // local unit 0..3
    const int u = b * 4 + ul;      // global hidden unit
    const int r = gate * H + u;    // row in the 4H gate matrix
    const int off = lane * 4;

    __shared__ float lds_iv[2 * H];   // staged [ff | recurrent] input vector
    __shared__ float lds_fc[H];       // this block's fc row
    __shared__ float gate_buf[16];
    __shared__ float c_store[12];     // [layer*4 + local_unit]

    float* hbuf = ws;                 // [2][3*H] ping-pong hidden states
    float* inp  = ws + 2 * 3 * H;     // [D] current step-input vector

    // ---- one-time: weights -> registers (84 VGPRs/lane) ----
    float4 wl0[5], wl1[8], wl2[8];
    wl0[0] = *(const float4*)(Wih0 + (size_t)r * 256 + off);
#pragma unroll
    for (int j = 1; j < 5; ++j)
        wl0[j] = *(const float4*)(Whh0 + (size_t)r * H + (j - 1) * 256 + off);
#pragma unroll
    for (int j = 0; j < 4; ++j) {
        wl1[j]     = *(const float4*)(Wih1 + (size_t)r * H + j * 256 + off);
        wl1[j + 4] = *(const float4*)(Whh1 + (size_t)r * H + j * 256 + off);
        wl2[j]     = *(const float4*)(Wih2 + (size_t)r * H + j * 256 + off);
        wl2[j + 4] = *(const float4*)(Whh2 + (size_t)r * H + j * 256 + off);
    }
    const float bias0 = b_ih[0 * 4 * H + r] + b_hh[0 * 4 * H + r];
    const float bias1 = b_ih[1 * 4 * H + r] + b_hh[1 * 4 * H + r];
    const float bias2 = b_ih[2 * 4 * H + r] + b_hh[2 * 4 * H + r];
    const float bfc_r = bfc[b];

    for (int i = tid; i < H; i += NT) lds_fc[i] = Wfc[(size_t)b * H + i];

    if (tid < 12) {
        int l = tid >> 2, j = tid & 3;
        c_store[tid] = c0[l * H + b * 4 + j];
        hbuf[0 * 3 * H + l * H + b * 4 + j] = h0[l * H + b * 4 + j];
    }
    if (tid == 0) {
        float v = x[(size_t)b * L];       // x[0, d=b, t=0]
        inp[b] = v;
        out[(size_t)b * T] = v;           // out column 0
    }
    __syncthreads();
    grid.sync();

#define DOT_PHASE(WREG, NJ, BIAS, LIDX)                                          \
    {                                                                            \
        float4 a = {0.f, 0.f, 0.f, 0.f};                                         \
        _Pragma("unroll")                                                        \
        for (int j = 0; j < NJ; ++j) {                                           \
            float4 v = *(const float4*)(lds_iv + j * 256 + off);                 \
            a.x += WREG[j].x * v.x; a.y += WREG[j].y * v.y;                      \
            a.z += WREG[j].z * v.z; a.w += WREG[j].w * v.w;                      \
        }                                                                        \
        float acc = waveReduce(a.x + a.y + a.z + a.w);                           \
        if (lane == 0) gate_buf[w] = acc + BIAS;                                 \
    }                                                                            \
    __syncthreads();                                                             \
    if (tid < 4) {                                                               \
        float gi = gate_buf[tid * 4 + 0], gf = gate_buf[tid * 4 + 1];            \
        float gg = gate_buf[tid * 4 + 2], go = gate_buf[tid * 4 + 3];            \
        float cn = sigf(gf) * c_store[(LIDX) * 4 + tid] + sigf(gi) * tanhf(gg);  \
        c_store[(LIDX) * 4 + tid] = cn;                                          \
        h_new[(LIDX) * H + b * 4 + tid] = sigf(go) * tanhf(cn);                  \
    }                                                                            \
    grid.sync();

    for (int s = 0; s < T - 1; ++s) {
        const int p = s & 1;
        const float* h_old = hbuf + p * 3 * H;
        float*       h_new = hbuf + (p ^ 1) * 3 * H;

        // ---- layer 0: iv = [inp(256) | h_old[0](1024)] ----
        for (int i = tid; i < 256 + H; i += NT)
            lds_iv[i] = (i < 256) ? inp[i] : h_old[0 * H + i - 256];
        __syncthreads();
        DOT_PHASE(wl0, 5, bias0, 0)

        // ---- layer 1: iv = [h_new[0] | h_old[1]] ----
        for (int i = tid; i < 2 * H; i += NT)
            lds_iv[i] = (i < H) ? h_new[0 * H + i] : h_old[1 * H + i - H];
        __syncthreads();
        DOT_PHASE(wl1, 8, bias1, 1)

        // ---- layer 2: iv = [h_new[1] | h_old[2]] ----
        for (int i = tid; i < 2 * H; i += NT)
            lds_iv[i] = (i < H) ? h_new[1 * H + i] : h_old[2 * H + i - H];
        __syncthreads();
        DOT_PHASE(wl2, 8, bias2, 2)

        // ---- fc / generation: wave 0, row b, reads h_new[2] from global ----
        if (w == 0) {
            float4 a = {0.f, 0.f, 0.f, 0.f};
#pragma unroll
            for (int j = 0; j < 4; ++j) {
                float4 v  = *(const float4*)(h_new + 2 * H + j * 256 + off);
                float4 wv = *(const float4*)(lds_fc + j * 256 + off);
                a.x += wv.x * v.x; a.y += wv.y * v.y;
                a.z += wv.z * v.z; a.w += wv.w * v.w;
            }
            float acc = waveReduce(a.x + a.y + a.z + a.w);
            if (lane == 0) {
                float gen = sigf(acc + bfc_r);
                float nxt = ((s + 1) < L) ? x[(size_t)b * L + (s + 1)] : gen;
                inp[b] = nxt;                       // input for step s+1
                out[(size_t)b * T + (s + 1)] = nxt; // out column s+1
            }
        }
        grid.sync();
    }
#undef DOT_PHASE
}

extern "C" void kernel_launch(void* const* d_in, const int* in_sizes, int n_in,
                              void* d_out, int out_size, void* d_ws, size_t ws_size,
                              hipStream_t stream) {
    const float* x    = (const float*)d_in[0];
    const float* h0   = (const float*)d_in[1];
    const float* c0   = (const float*)d_in[2];
    const float* Wih0 = (const float*)d_in[3];
    const float* Whh0 = (const float*)d_in[4];
    const float* Wih1 = (const float*)d_in[5];
    const float* Whh1 = (const float*)d_in[6];
    const float* Wih2 = (const float*)d_in[7];
    const float* Whh2 = (const float*)d_in[8];
    const float* bih  = (const float*)d_in[9];
    const float* bhh  = (const float*)d_in[10];
    const float* Wfc  = (const float*)d_in[11];
    const float* bfc  = (const float*)d_in[12];

    float* out = (float*)d_out;
    float* ws  = (float*)d_ws;

    int T = out_size / D;        // 2048
    int L = in_sizes[0] / D;     // 64

    void* args[] = { &x, &h0, &c0, &Wih0, &Whh0, &Wih1, &Whh1, &Wih2, &Whh2,
                     &bih, &bhh, &Wfc, &bfc, &out, &ws, &T, &L };

    hipLaunchCooperativeKernel((void*)rnn_reg, dim3(NB), dim3(NT), args, 0, stream);
}

// Round 4
// 73215.631 us; speedup vs baseline: 6.0326x; 3.1138x over previous
//
#include <hip/hip_runtime.h>
#include <math.h>

#define H 1024
#define D 256
#define NB 256
#define NT 512

__device__ __forceinline__ float sigf(float v) { return 1.f / (1.f + __expf(-v)); }

__device__ __forceinline__ float waveReduce(float v) {
#pragma unroll
    for (int off = 32; off > 0; off >>= 1) v += __shfl_xor(v, off, 64);
    return v;
}

// ---- workspace layout (floats) ----
// [0]        barrier arrival counter (unsigned)
// [64]       barrier generation      (unsigned)   (separate 256B line)
// [128 .. 128+6H)   hbuf ping-pong [2][3H]
// [128+6H .. +D)    inp vector

__global__ void bar_init(unsigned* wsu) {
    __hip_atomic_store(&wsu[0], 0u, __ATOMIC_RELAXED, __HIP_MEMORY_SCOPE_AGENT);
    __hip_atomic_store(&wsu[64], 0u, __ATOMIC_RELAXED, __HIP_MEMORY_SCOPE_AGENT);
}

__device__ __forceinline__ void gbar(unsigned* cnt, unsigned* gen) {
    __syncthreads();   // all block stores issued before fence
    if (threadIdx.x == 0) {
        unsigned g = __hip_atomic_load(gen, __ATOMIC_RELAXED, __HIP_MEMORY_SCOPE_AGENT);
        __builtin_amdgcn_fence(__ATOMIC_RELEASE, "agent");   // flush caches -> visible device-wide
        unsigned my = __hip_atomic_fetch_add(cnt, 1u, __ATOMIC_RELAXED, __HIP_MEMORY_SCOPE_AGENT);
        if (my == NB - 1) {
            __hip_atomic_store(cnt, 0u, __ATOMIC_RELAXED, __HIP_MEMORY_SCOPE_AGENT);
            // release: counter reset must be visible before generation flips
            __hip_atomic_store(gen, g + 1u, __ATOMIC_RELEASE, __HIP_MEMORY_SCOPE_AGENT);
        } else {
            while (__hip_atomic_load(gen, __ATOMIC_RELAXED, __HIP_MEMORY_SCOPE_AGENT) == g)
                __builtin_amdgcn_s_sleep(1);
        }
        __builtin_amdgcn_fence(__ATOMIC_ACQUIRE, "agent");   // invalidate stale cache lines
    }
    __syncthreads();
}

__global__ __launch_bounds__(NT, 2) void rnn_reg2(
    const float* __restrict__ x, const float* __restrict__ h0, const float* __restrict__ c0,
    const float* __restrict__ Wih0, const float* __restrict__ Whh0,
    const float* __restrict__ Wih1, const float* __restrict__ Whh1,
    const float* __restrict__ Wih2, const float* __restrict__ Whh2,
    const float* __restrict__ b_ih, const float* __restrict__ b_hh,
    const float* __restrict__ Wfc, const float* __restrict__ bfc,
    float* __restrict__ out, float* __restrict__ ws,
    int T, int L)
{
    const int b = blockIdx.x;
    const int tid = threadIdx.x;
    const int w = tid >> 6;
    const int lane = tid & 63;
    const int gate = w & 3;          // i,f,g,o
    const int up = w >> 2;           // 0..1 -> unit pair
    const int u0 = b * 4 + 2 * up;   // this wave's two hidden units
    const int r0 = gate * H + u0;
    const int r1 = r0 + 1;
    const int off = lane * 4;

    unsigned* cnt = (unsigned*)ws;
    unsigned* gen = (unsigned*)ws + 64;
    float* hbuf = ws + 128;
    float* inp  = ws + 128 + 6 * H;

    __shared__ float lds_iv[2 * H];
    __shared__ float lds_fc[H];
    __shared__ float gate_buf[16];   // [unit_local][gate]
    __shared__ float c_st[12];       // [layer][unit_local]

    // ---- one-time: weights -> registers (2 rows/wave, 42 float4 = 168 VGPR) ----
    float4 wA0[5], wB0[5], wA1[8], wB1[8], wA2[8], wB2[8];
    wA0[0] = *(const float4*)(Wih0 + (size_t)r0 * 256 + off);
    wB0[0] = *(const float4*)(Wih0 + (size_t)r1 * 256 + off);
#pragma unroll
    for (int j = 0; j < 4; ++j) {
        wA0[j + 1] = *(const float4*)(Whh0 + (size_t)r0 * H + j * 256 + off);
        wB0[j + 1] = *(const float4*)(Whh0 + (size_t)r1 * H + j * 256 + off);
        wA1[j]     = *(const float4*)(Wih1 + (size_t)r0 * H + j * 256 + off);
        wB1[j]     = *(const float4*)(Wih1 + (size_t)r1 * H + j * 256 + off);
        wA1[j + 4] = *(const float4*)(Whh1 + (size_t)r0 * H + j * 256 + off);
        wB1[j + 4] = *(const float4*)(Whh1 + (size_t)r1 * H + j * 256 + off);
        wA2[j]     = *(const float4*)(Wih2 + (size_t)r0 * H + j * 256 + off);
        wB2[j]     = *(const float4*)(Wih2 + (size_t)r1 * H + j * 256 + off);
        wA2[j + 4] = *(const float4*)(Whh2 + (size_t)r0 * H + j * 256 + off);
        wB2[j + 4] = *(const float4*)(Whh2 + (size_t)r1 * H + j * 256 + off);
    }
    const float bA0 = b_ih[r0] + b_hh[r0];
    const float bB0 = b_ih[r1] + b_hh[r1];
    const float bA1 = b_ih[4 * H + r0] + b_hh[4 * H + r0];
    const float bB1 = b_ih[4 * H + r1] + b_hh[4 * H + r1];
    const float bA2 = b_ih[8 * H + r0] + b_hh[8 * H + r0];
    const float bB2 = b_ih[8 * H + r1] + b_hh[8 * H + r1];
    const float bfc_b = bfc[b];

    // keep-alive: make remat of these loads illegal (forces register residency)
#define KA(v) asm volatile("" : "+v"(v.x), "+v"(v.y), "+v"(v.z), "+v"(v.w))
#pragma unroll
    for (int j = 0; j < 5; ++j) { KA(wA0[j]); KA(wB0[j]); }
#pragma unroll
    for (int j = 0; j < 8; ++j) { KA(wA1[j]); KA(wB1[j]); KA(wA2[j]); KA(wB2[j]); }
#undef KA

    for (int i = tid; i < H; i += NT) lds_fc[i] = Wfc[(size_t)b * H + i];

    if (tid < 12) {
        int l = tid >> 2, j = tid & 3;
        c_st[tid] = c0[l * H + b * 4 + j];
        hbuf[l * H + b * 4 + j] = h0[l * H + b * 4 + j];   // ping buffer 0
    }
    if (tid == 0) {
        float v = x[(size_t)b * L];
        inp[b] = v;
        out[(size_t)b * T] = v;   // out column 0
    }
    gbar(cnt, gen);

#define DOT_COMBINE(WREGA, WREGB, NJ, BIASA, BIASB, LIDX)                         \
    {                                                                             \
        float4 a0 = {0.f, 0.f, 0.f, 0.f}, a1 = {0.f, 0.f, 0.f, 0.f};             \
        _Pragma("unroll")                                                         \
        for (int j = 0; j < NJ; ++j) {                                            \
            float4 v = *(const float4*)(lds_iv + j * 256 + off);                  \
            a0.x += WREGA[j].x * v.x; a0.y += WREGA[j].y * v.y;                   \
            a0.z += WREGA[j].z * v.z; a0.w += WREGA[j].w * v.w;                   \
            a1.x += WREGB[j].x * v.x; a1.y += WREGB[j].y * v.y;                   \
            a1.z += WREGB[j].z * v.z; a1.w += WREGB[j].w * v.w;                   \
        }                                                                         \
        float s0 = waveReduce(a0.x + a0.y + a0.z + a0.w);                         \
        float s1 = waveReduce(a1.x + a1.y + a1.z + a1.w);                         \
        if (lane == 0) {                                                          \
            gate_buf[(2 * up) * 4 + gate]     = s0 + BIASA;                       \
            gate_buf[(2 * up + 1) * 4 + gate] = s1 + BIASB;                       \
        }                                                                         \
    }                                                                             \
    __syncthreads();                                                              \
    if (tid < 4) {                                                                \
        float gi = gate_buf[tid * 4 + 0], gf = gate_buf[tid * 4 + 1];             \
        float gg = gate_buf[tid * 4 + 2], go = gate_buf[tid * 4 + 3];             \
        float cn = sigf(gf) * c_st[(LIDX) * 4 + tid] + sigf(gi) * tanhf(gg);      \
        c_st[(LIDX) * 4 + tid] = cn;                                              \
        h_new[(LIDX) * H + b * 4 + tid] = sigf(go) * tanhf(cn);                   \
    }                                                                             \
    gbar(cnt, gen);

    for (int s = 0; s < T - 1; ++s) {
        const int p = s & 1;
        const float* h_old = hbuf + p * 3 * H;
        float*       h_new = hbuf + (p ^ 1) * 3 * H;

        // ---- layer 0: iv = [inp(256) | h_old0(1024)] ----
        if (tid < 320) {
            float4 v;
            if (tid < 64) v = *(const float4*)(inp + tid * 4);
            else          v = *(const float4*)(h_old + (tid - 64) * 4);
            *(float4*)(lds_iv + tid * 4) = v;
        }
        __syncthreads();
        DOT_COMBINE(wA0, wB0, 5, bA0, bB0, 0)

        // ---- layer 1: iv = [h_new0 | h_old1] ----
        {
            int i = tid * 4;
            float4 v;
            if (i < H) v = *(const float4*)(h_new + i);
            else       v = *(const float4*)(h_old + H + (i - H));
            *(float4*)(lds_iv + i) = v;
        }
        __syncthreads();
        DOT_COMBINE(wA1, wB1, 8, bA1, bB1, 1)

        // ---- layer 2: iv = [h_new1 | h_old2] ----
        {
            int i = tid * 4;
            float4 v;
            if (i < H) v = *(const float4*)(h_new + H + i);
            else       v = *(const float4*)(h_old + 2 * H + (i - H));
            *(float4*)(lds_iv + i) = v;
        }
        __syncthreads();
        DOT_COMBINE(wA2, wB2, 8, bA2, bB2, 2)

        // ---- fc / generation: wave 0, row b ----
        if (w == 0) {
            float4 a = {0.f, 0.f, 0.f, 0.f};
#pragma unroll
            for (int j = 0; j < 4; ++j) {
                float4 v  = *(const float4*)(h_new + 2 * H + j * 256 + off);
                float4 fw = *(const float4*)(lds_fc + j * 256 + off);
                a.x += fw.x * v.x; a.y += fw.y * v.y;
                a.z += fw.z * v.z; a.w += fw.w * v.w;
            }
            float sfc = waveReduce(a.x + a.y + a.z + a.w);
            if (lane == 0) {
                float gv = sigf(sfc + bfc_b);
                float nxt = ((s + 1) < L) ? x[(size_t)b * L + (s + 1)] : gv;
                inp[b] = nxt;
                out[(size_t)b * T + (s + 1)] = nxt;
            }
        }
        gbar(cnt, gen);
    }
#undef DOT_COMBINE
}

extern "C" void kernel_launch(void* const* d_in, const int* in_sizes, int n_in,
                              void* d_out, int out_size, void* d_ws, size_t ws_size,
                              hipStream_t stream) {
    const float* x    = (const float*)d_in[0];
    const float* h0   = (const float*)d_in[1];
    const float* c0   = (const float*)d_in[2];
    const float* Wih0 = (const float*)d_in[3];
    const float* Whh0 = (const float*)d_in[4];
    const float* Wih1 = (const float*)d_in[5];
    const float* Whh1 = (const float*)d_in[6];
    const float* Wih2 = (const float*)d_in[7];
    const float* Whh2 = (const float*)d_in[8];
    const float* bih  = (const float*)d_in[9];
    const float* bhh  = (const float*)d_in[10];
    const float* Wfc  = (const float*)d_in[11];
    const float* bfc  = (const float*)d_in[12];

    float* out = (float*)d_out;
    float* ws  = (float*)d_ws;

    int T = out_size / D;        // 2048
    int L = in_sizes[0] / D;     // 64

    bar_init<<<1, 1, 0, stream>>>((unsigned*)d_ws);

    void* args[] = { &x, &h0, &c0, &Wih0, &Whh0, &Wih1, &Whh1, &Wih2, &Whh2,
                     &bih, &bhh, &Wfc, &bfc, &out, &ws, &T, &L };

    (void)hipLaunchCooperativeKernel((void*)rnn_reg2, dim3(NB), dim3(NT), args, 0, stream);
}

// Round 5
// 39011.740 us; speedup vs baseline: 11.3218x; 1.8768x over previous
//
#include <hip/hip_runtime.h>
#include <math.h>

#define H 1024
#define D 256
#define NB 256
#define NT 512

__device__ __forceinline__ float sigf(float v) { return 1.f / (1.f + __expf(-v)); }

__device__ __forceinline__ float waveReduce(float v) {
#pragma unroll
    for (int off = 32; off > 0; off >>= 1) v += __shfl_xor(v, off, 64);
    return v;
}

// Coherent (LLC-level) access helpers: sc0 sc1 flags bypass L1/L2 so no
// buffer_wbl2 / buffer_inv cache maintenance is ever needed.
__device__ __forceinline__ float4 ldg4_cg(const float* p) {
    float4 r;
    asm volatile("global_load_dwordx4 %0, %1, off sc0 sc1\n\ts_waitcnt vmcnt(0)"
                 : "=v"(r) : "v"(p) : "memory");
    return r;
}
__device__ __forceinline__ void stg_cg(float* p, float v) {
    __hip_atomic_store(p, v, __ATOMIC_RELAXED, __HIP_MEMORY_SCOPE_AGENT);
}

// ---- workspace layout (floats) ----
// [0]    barrier arrival counter (unsigned, monotonic)
// [64]   barrier generation      (unsigned, monotonic)  (separate 256B line)
// [128 .. 128+6H)   hbuf ping-pong [2][3H]
// [128+6H .. +D)    inp vector

__global__ void bar_init(unsigned* wsu) {
    __hip_atomic_store(&wsu[0], 0u, __ATOMIC_RELAXED, __HIP_MEMORY_SCOPE_AGENT);
    __hip_atomic_store(&wsu[64], 0u, __ATOMIC_RELAXED, __HIP_MEMORY_SCOPE_AGENT);
}

// Sense-free monotonic barrier. __syncthreads() drains vmcnt for every wave
// (compiler emits s_waitcnt vmcnt(0) before s_barrier), so all sc-flagged data
// stores are LLC-visible before tid0 arrives. No cache fences required.
__device__ __forceinline__ void gbar(unsigned* cnt, unsigned* gen, unsigned phase) {
    __syncthreads();
    if (threadIdx.x == 0) {
        unsigned old = __hip_atomic_fetch_add(cnt, 1u, __ATOMIC_RELAXED, __HIP_MEMORY_SCOPE_AGENT);
        if (old == phase * NB - 1u) {
            __hip_atomic_store(gen, phase, __ATOMIC_RELAXED, __HIP_MEMORY_SCOPE_AGENT);
        } else {
            unsigned g;
            do {
                __builtin_amdgcn_s_sleep(2);
                g = __hip_atomic_load(gen, __ATOMIC_RELAXED, __HIP_MEMORY_SCOPE_AGENT);
            } while ((int)(g - phase) < 0);
        }
    }
    __syncthreads();
}

__global__ __launch_bounds__(NT, 2) void rnn_reg3(
    const float* __restrict__ x, const float* __restrict__ h0, const float* __restrict__ c0,
    const float* __restrict__ Wih0, const float* __restrict__ Whh0,
    const float* __restrict__ Wih1, const float* __restrict__ Whh1,
    const float* __restrict__ Wih2, const float* __restrict__ Whh2,
    const float* __restrict__ b_ih, const float* __restrict__ b_hh,
    const float* __restrict__ Wfc, const float* __restrict__ bfc,
    float* __restrict__ out, float* __restrict__ ws,
    int T, int L)
{
    const int b = blockIdx.x;
    const int tid = threadIdx.x;
    const int w = tid >> 6;
    const int lane = tid & 63;
    const int gate = w & 3;          // i,f,g,o
    const int up = w >> 2;           // 0..1 -> unit pair
    const int u0 = b * 4 + 2 * up;   // this wave's two hidden units
    const int r0 = gate * H + u0;
    const int r1 = r0 + 1;
    const int off = lane * 4;

    unsigned* cnt = (unsigned*)ws;
    unsigned* gen = (unsigned*)ws + 64;
    float* hbuf = ws + 128;
    float* inp  = ws + 128 + 6 * H;
    unsigned ph = 0;

    __shared__ float lds_iv[2 * H];
    __shared__ float lds_fc[H];
    __shared__ float gate_buf[16];   // [unit_local][gate]
    __shared__ float c_st[12];       // [layer][unit_local]

    // ---- one-time: weights -> registers (2 rows/wave, 42 float4) ----
    float4 wA0[5], wB0[5], wA1[8], wB1[8], wA2[8], wB2[8];
    wA0[0] = *(const float4*)(Wih0 + (size_t)r0 * 256 + off);
    wB0[0] = *(const float4*)(Wih0 + (size_t)r1 * 256 + off);
#pragma unroll
    for (int j = 0; j < 4; ++j) {
        wA0[j + 1] = *(const float4*)(Whh0 + (size_t)r0 * H + j * 256 + off);
        wB0[j + 1] = *(const float4*)(Whh0 + (size_t)r1 * H + j * 256 + off);
        wA1[j]     = *(const float4*)(Wih1 + (size_t)r0 * H + j * 256 + off);
        wB1[j]     = *(const float4*)(Wih1 + (size_t)r1 * H + j * 256 + off);
        wA1[j + 4] = *(const float4*)(Whh1 + (size_t)r0 * H + j * 256 + off);
        wB1[j + 4] = *(const float4*)(Whh1 + (size_t)r1 * H + j * 256 + off);
        wA2[j]     = *(const float4*)(Wih2 + (size_t)r0 * H + j * 256 + off);
        wB2[j]     = *(const float4*)(Wih2 + (size_t)r1 * H + j * 256 + off);
        wA2[j + 4] = *(const float4*)(Whh2 + (size_t)r0 * H + j * 256 + off);
        wB2[j + 4] = *(const float4*)(Whh2 + (size_t)r1 * H + j * 256 + off);
    }
    const float bA0 = b_ih[r0] + b_hh[r0];
    const float bB0 = b_ih[r1] + b_hh[r1];
    const float bA1 = b_ih[4 * H + r0] + b_hh[4 * H + r0];
    const float bB1 = b_ih[4 * H + r1] + b_hh[4 * H + r1];
    const float bA2 = b_ih[8 * H + r0] + b_hh[8 * H + r0];
    const float bB2 = b_ih[8 * H + r1] + b_hh[8 * H + r1];
    const float bfc_b = bfc[b];

    // keep-alive: make remat of these loads illegal (forces on-chip residency)
#define KA(v) asm volatile("" : "+v"(v.x), "+v"(v.y), "+v"(v.z), "+v"(v.w))
#pragma unroll
    for (int j = 0; j < 5; ++j) { KA(wA0[j]); KA(wB0[j]); }
#pragma unroll
    for (int j = 0; j < 8; ++j) { KA(wA1[j]); KA(wB1[j]); KA(wA2[j]); KA(wB2[j]); }
#undef KA

    for (int i = tid; i < H; i += NT) lds_fc[i] = Wfc[(size_t)b * H + i];

    if (tid < 12) {
        int l = tid >> 2, j = tid & 3;
        c_st[tid] = c0[l * H + b * 4 + j];
        stg_cg(&hbuf[l * H + b * 4 + j], h0[l * H + b * 4 + j]);  // ping buffer 0
    }
    if (tid == 0) {
        float v = x[(size_t)b * L];
        stg_cg(&inp[b], v);
        out[(size_t)b * T] = v;   // out column 0 (only read by host)
    }
    ++ph; gbar(cnt, gen, ph);

#define DOT_COMBINE(WREGA, WREGB, NJ, BIASA, BIASB, LIDX)                         \
    {                                                                             \
        float4 a0 = {0.f, 0.f, 0.f, 0.f}, a1 = {0.f, 0.f, 0.f, 0.f};             \
        _Pragma("unroll")                                                         \
        for (int j = 0; j < NJ; ++j) {                                            \
            float4 v = *(const float4*)(lds_iv + j * 256 + off);                  \
            a0.x += WREGA[j].x * v.x; a0.y += WREGA[j].y * v.y;                   \
            a0.z += WREGA[j].z * v.z; a0.w += WREGA[j].w * v.w;                   \
            a1.x += WREGB[j].x * v.x; a1.y += WREGB[j].y * v.y;                   \
            a1.z += WREGB[j].z * v.z; a1.w += WREGB[j].w * v.w;                   \
        }                                                                         \
        float s0 = waveReduce(a0.x + a0.y + a0.z + a0.w);                         \
        float s1 = waveReduce(a1.x + a1.y + a1.z + a1.w);                         \
        if (lane == 0) {                                                          \
            gate_buf[(2 * up) * 4 + gate]     = s0 + BIASA;                       \
            gate_buf[(2 * up + 1) * 4 + gate] = s1 + BIASB;                       \
        }                                                                         \
    }                                                                             \
    __syncthreads();                                                              \
    if (tid < 4) {                                                                \
        float gi = gate_buf[tid * 4 + 0], gf = gate_buf[tid * 4 + 1];             \
        float gg = gate_buf[tid * 4 + 2], go = gate_buf[tid * 4 + 3];             \
        float cn = sigf(gf) * c_st[(LIDX) * 4 + tid] + sigf(gi) * tanhf(gg);      \
        c_st[(LIDX) * 4 + tid] = cn;                                              \
        stg_cg(&h_new[(LIDX) * H + b * 4 + tid], sigf(go) * tanhf(cn));           \
    }                                                                             \
    ++ph; gbar(cnt, gen, ph);

    for (int s = 0; s < T - 1; ++s) {
        const int p = s & 1;
        const float* h_old = hbuf + p * 3 * H;
        float*       h_new = hbuf + (p ^ 1) * 3 * H;

        // ---- layer 0: iv = [inp(256) | h_old0(1024)] ----
        if (tid < 320) {
            float4 v = (tid < 64) ? ldg4_cg(inp + tid * 4)
                                  : ldg4_cg(h_old + (tid - 64) * 4);
            *(float4*)(lds_iv + tid * 4) = v;
        }
        __syncthreads();
        DOT_COMBINE(wA0, wB0, 5, bA0, bB0, 0)

        // ---- layer 1: iv = [h_new0 | h_old1] ----
        {
            int i = tid * 4;
            float4 v = (i < H) ? ldg4_cg(h_new + i)
                               : ldg4_cg(h_old + H + (i - H));
            *(float4*)(lds_iv + i) = v;
        }
        __syncthreads();
        DOT_COMBINE(wA1, wB1, 8, bA1, bB1, 1)

        // ---- layer 2: iv = [h_new1 | h_old2] ----
        {
            int i = tid * 4;
            float4 v = (i < H) ? ldg4_cg(h_new + H + i)
                               : ldg4_cg(h_old + 2 * H + (i - H));
            *(float4*)(lds_iv + i) = v;
        }
        __syncthreads();
        DOT_COMBINE(wA2, wB2, 8, bA2, bB2, 2)

        // ---- fc / generation: wave 0, row b ----
        if (w == 0) {
            float4 a = {0.f, 0.f, 0.f, 0.f};
#pragma unroll
            for (int j = 0; j < 4; ++j) {
                float4 v  = ldg4_cg(h_new + 2 * H + j * 256 + off);
                float4 fw = *(const float4*)(lds_fc + j * 256 + off);
                a.x += fw.x * v.x; a.y += fw.y * v.y;
                a.z += fw.z * v.z; a.w += fw.w * v.w;
            }
            float sfc = waveReduce(a.x + a.y + a.z + a.w);
            if (lane == 0) {
                float gv = sigf(sfc + bfc_b);
                float nxt = ((s + 1) < L) ? x[(size_t)b * L + (s + 1)] : gv;
                stg_cg(&inp[b], nxt);
                out[(size_t)b * T + (s + 1)] = nxt;
            }
        }
        ++ph; gbar(cnt, gen, ph);
    }
#undef DOT_COMBINE
}

extern "C" void kernel_launch(void* const* d_in, const int* in_sizes, int n_in,
                              void* d_out, int out_size, void* d_ws, size_t ws_size,
                              hipStream_t stream) {
    const float* x    = (const float*)d_in[0];
    const float* h0   = (const float*)d_in[1];
    const float* c0   = (const float*)d_in[2];
    const float* Wih0 = (const float*)d_in[3];
    const float* Whh0 = (const float*)d_in[4];
    const float* Wih1 = (const float*)d_in[5];
    const float* Whh1 = (const float*)d_in[6];
    const float* Wih2 = (const float*)d_in[7];
    const float* Whh2 = (const float*)d_in[8];
    const float* bih  = (const float*)d_in[9];
    const float* bhh  = (const float*)d_in[10];
    const float* Wfc  = (const float*)d_in[11];
    const float* bfc  = (const float*)d_in[12];

    float* out = (float*)d_out;
    float* ws  = (float*)d_ws;

    int T = out_size / D;        // 2048
    int L = in_sizes[0] / D;     // 64

    bar_init<<<1, 1, 0, stream>>>((unsigned*)d_ws);

    void* args[] = { &x, &h0, &c0, &Wih0, &Whh0, &Wih1, &Whh1, &Wih2, &Whh2,
                     &bih, &bhh, &Wfc, &bfc, &out, &ws, &T, &L };

    (void)hipLaunchCooperativeKernel((void*)rnn_reg3, dim3(NB), dim3(NT), args, 0, stream);
}

// Round 6
// 19597.469 us; speedup vs baseline: 22.5377x; 1.9907x over previous
//
#include <hip/hip_runtime.h>
#include <math.h>

#define H 1024
#define D 256
#define NB 256
#define NT 512

__device__ __forceinline__ float sigf(float v) { return 1.f / (1.f + __expf(-v)); }

__device__ __forceinline__ float waveReduce(float v) {
#pragma unroll
    for (int off = 32; off > 0; off >>= 1) v += __shfl_xor(v, off, 64);
    return v;
}

// Coherent LLC-level loads (sc0 sc1 bypass L1/L2). Issue/wait split so multiple
// loads overlap with a single vmcnt drain.
__device__ __forceinline__ float4 ldg4_issue(const float* p) {
    float4 r;
    asm volatile("global_load_dwordx4 %0, %1, off sc0 sc1" : "=v"(r) : "v"(p) : "memory");
    return r;
}
__device__ __forceinline__ void vm_wait() { asm volatile("s_waitcnt vmcnt(0)" ::: "memory"); }
__device__ __forceinline__ float4 ldg4_cg(const float* p) {
    float4 r = ldg4_issue(p);
    vm_wait();
    return r;
}
__device__ __forceinline__ void stg_cg(float* p, float v) {
    __hip_atomic_store(p, v, __ATOMIC_RELAXED, __HIP_MEMORY_SCOPE_AGENT);
}

// ---- workspace layout (32-bit words) ----
// [0 .. 4096)        arrival flags: flag[b] at word b*16 (64B apart), monotonic phase
// [4096]             generation word (own line), monotonic phase
// [4352 .. +6H)      hbuf ping-pong [2][3H] floats
// [4352+6H .. +D)    inp vector floats

__global__ void bar_init(unsigned* wsu) {
    for (int i = threadIdx.x; i < 4352; i += blockDim.x)
        __hip_atomic_store(&wsu[i], 0u, __ATOMIC_RELAXED, __HIP_MEMORY_SCOPE_AGENT);
}

// Flag-array barrier: parallel arrivals, block0 combines, single broadcast.
// __syncthreads() drains vmcnt (sc-flagged data stores already at LLC).
__device__ __forceinline__ void gbar(unsigned* flags, unsigned* gen, unsigned phase) {
    __syncthreads();
    if (blockIdx.x == 0) {
        const int t = threadIdx.x;
        if (t > 0 && t < NB) {
            while (__hip_atomic_load(&flags[t * 16], __ATOMIC_RELAXED, __HIP_MEMORY_SCOPE_AGENT) < phase)
                __builtin_amdgcn_s_sleep(1);
        }
        __syncthreads();
        if (t == 0)
            __hip_atomic_store(gen, phase, __ATOMIC_RELAXED, __HIP_MEMORY_SCOPE_AGENT);
    } else {
        if (threadIdx.x == 0) {
            __hip_atomic_store(&flags[blockIdx.x * 16], phase, __ATOMIC_RELAXED, __HIP_MEMORY_SCOPE_AGENT);
            while (__hip_atomic_load(gen, __ATOMIC_RELAXED, __HIP_MEMORY_SCOPE_AGENT) < phase)
                __builtin_amdgcn_s_sleep(1);
        }
        __syncthreads();
    }
}

__global__ __launch_bounds__(NT, 2) void rnn_reg4(
    const float* __restrict__ x, const float* __restrict__ h0, const float* __restrict__ c0,
    const float* __restrict__ Wih0, const float* __restrict__ Whh0,
    const float* __restrict__ Wih1, const float* __restrict__ Whh1,
    const float* __restrict__ Wih2, const float* __restrict__ Whh2,
    const float* __restrict__ b_ih, const float* __restrict__ b_hh,
    const float* __restrict__ Wfc, const float* __restrict__ bfc,
    float* __restrict__ out, float* __restrict__ ws,
    int T, int L)
{
    const int b = blockIdx.x;
    const int tid = threadIdx.x;
    const int w = tid >> 6;
    const int lane = tid & 63;
    const int gate = w & 3;          // i,f,g,o
    const int up = w >> 2;           // 0..1 -> unit pair
    const int u0 = b * 4 + 2 * up;   // this wave's two hidden units
    const int r0 = gate * H + u0;
    const int r1 = r0 + 1;
    const int off = lane * 4;

    unsigned* flags = (unsigned*)ws;
    unsigned* gen   = (unsigned*)ws + 4096;
    float* hbuf = ws + 4352;
    float* inp  = ws + 4352 + 6 * H;
    unsigned ph = 0;

    __shared__ float lds_inp[256];     // fresh step input (layer-0 ff part)
    __shared__ float lds_fresh[H];     // freshly produced h (ff input to layer 1/2)
    __shared__ float lds_hpf[3 * H];   // pre-staged h_old for all 3 layers
    __shared__ float lds_fc[H];        // this block's fc row
    __shared__ float gate_buf[16];     // [unit_local][gate]
    __shared__ float red[8];           // fc per-wave partials
    __shared__ float c_st[12];         // [layer][unit_local]

    // ---- one-time: weights -> registers (2 rows/wave, 42 float4) ----
    float4 wA0[5], wB0[5], wA1[8], wB1[8], wA2[8], wB2[8];
    wA0[0] = *(const float4*)(Wih0 + (size_t)r0 * 256 + off);
    wB0[0] = *(const float4*)(Wih0 + (size_t)r1 * 256 + off);
#pragma unroll
    for (int j = 0; j < 4; ++j) {
        wA0[j + 1] = *(const float4*)(Whh0 + (size_t)r0 * H + j * 256 + off);
        wB0[j + 1] = *(const float4*)(Whh0 + (size_t)r1 * H + j * 256 + off);
        wA1[j]     = *(const float4*)(Wih1 + (size_t)r0 * H + j * 256 + off);
        wB1[j]     = *(const float4*)(Wih1 + (size_t)r1 * H + j * 256 + off);
        wA1[j + 4] = *(const float4*)(Whh1 + (size_t)r0 * H + j * 256 + off);
        wB1[j + 4] = *(const float4*)(Whh1 + (size_t)r1 * H + j * 256 + off);
        wA2[j]     = *(const float4*)(Wih2 + (size_t)r0 * H + j * 256 + off);
        wB2[j]     = *(const float4*)(Wih2 + (size_t)r1 * H + j * 256 + off);
        wA2[j + 4] = *(const float4*)(Whh2 + (size_t)r0 * H + j * 256 + off);
        wB2[j + 4] = *(const float4*)(Whh2 + (size_t)r1 * H + j * 256 + off);
    }
    const float bA0 = b_ih[r0] + b_hh[r0];
    const float bB0 = b_ih[r1] + b_hh[r1];
    const float bA1 = b_ih[4 * H + r0] + b_hh[4 * H + r0];
    const float bB1 = b_ih[4 * H + r1] + b_hh[4 * H + r1];
    const float bA2 = b_ih[8 * H + r0] + b_hh[8 * H + r0];
    const float bB2 = b_ih[8 * H + r1] + b_hh[8 * H + r1];
    const float bfc_b = bfc[b];

#define KA(v) asm volatile("" : "+v"(v.x), "+v"(v.y), "+v"(v.z), "+v"(v.w))
#pragma unroll
    for (int j = 0; j < 5; ++j) { KA(wA0[j]); KA(wB0[j]); }
#pragma unroll
    for (int j = 0; j < 8; ++j) { KA(wA1[j]); KA(wB1[j]); KA(wA2[j]); KA(wB2[j]); }
#undef KA

    for (int i = tid; i < H; i += NT) lds_fc[i] = Wfc[(size_t)b * H + i];

    if (tid < 12) {
        int l = tid >> 2, j = tid & 3;
        c_st[tid] = c0[l * H + b * 4 + j];
        stg_cg(&hbuf[l * H + b * 4 + j], h0[l * H + b * 4 + j]);  // ping buffer 0
    }
    if (tid == 0) {
        float v = x[(size_t)b * L];
        stg_cg(&inp[b], v);
        out[(size_t)b * T] = v;   // out column 0 (host-read only)
    }
    ++ph; gbar(flags, gen, ph);

    // prologue: pre-stage initial h states for step 0
    {
        float4 va = ldg4_issue(hbuf + tid * 4);
        float4 vb = {0.f, 0.f, 0.f, 0.f};
        if (tid < 256) vb = ldg4_issue(hbuf + 2048 + tid * 4);
        vm_wait();
        *(float4*)(lds_hpf + tid * 4) = va;
        if (tid < 256) *(float4*)(lds_hpf + 2048 + tid * 4) = vb;
    }

#define DOT2(WA, WB, N1, P1, N2, P2, BIASA, BIASB, LIDX)                          \
    {                                                                             \
        float4 a0 = {0.f, 0.f, 0.f, 0.f}, a1 = {0.f, 0.f, 0.f, 0.f};             \
        _Pragma("unroll")                                                         \
        for (int j = 0; j < N1; ++j) {                                            \
            float4 v = *(const float4*)((P1) + j * 256 + off);                    \
            a0.x += WA[j].x * v.x; a0.y += WA[j].y * v.y;                         \
            a0.z += WA[j].z * v.z; a0.w += WA[j].w * v.w;                         \
            a1.x += WB[j].x * v.x; a1.y += WB[j].y * v.y;                         \
            a1.z += WB[j].z * v.z; a1.w += WB[j].w * v.w;                         \
        }                                                                         \
        _Pragma("unroll")                                                         \
        for (int j = 0; j < N2; ++j) {                                            \
            float4 v = *(const float4*)((P2) + j * 256 + off);                    \
            a0.x += WA[N1 + j].x * v.x; a0.y += WA[N1 + j].y * v.y;               \
            a0.z += WA[N1 + j].z * v.z; a0.w += WA[N1 + j].w * v.w;               \
            a1.x += WB[N1 + j].x * v.x; a1.y += WB[N1 + j].y * v.y;               \
            a1.z += WB[N1 + j].z * v.z; a1.w += WB[N1 + j].w * v.w;               \
        }                                                                         \
        float s0 = waveReduce(a0.x + a0.y + a0.z + a0.w);                         \
        float s1 = waveReduce(a1.x + a1.y + a1.z + a1.w);                         \
        if (lane == 0) {                                                          \
            gate_buf[(2 * up) * 4 + gate]     = s0 + BIASA;                       \
            gate_buf[(2 * up + 1) * 4 + gate] = s1 + BIASB;                       \
        }                                                                         \
    }                                                                             \
    __syncthreads();                                                              \
    if (tid < 4) {                                                                \
        float gi = gate_buf[tid * 4 + 0], gf = gate_buf[tid * 4 + 1];             \
        float gg = gate_buf[tid * 4 + 2], go = gate_buf[tid * 4 + 3];             \
        float cn = sigf(gf) * c_st[(LIDX) * 4 + tid] + sigf(gi) * tanhf(gg);      \
        c_st[(LIDX) * 4 + tid] = cn;                                              \
        stg_cg(&h_new[(LIDX) * H + b * 4 + tid], sigf(go) * tanhf(cn));           \
    }                                                                             \
    ++ph; gbar(flags, gen, ph);

    for (int s = 0; s < T - 1; ++s) {
        const int p = s & 1;
        float* h_new = hbuf + (p ^ 1) * 3 * H;

        // ---- phase A: layer 0 (ff: inp, rec: lds_hpf[0]) ----
        if (tid < 64) {
            float4 v = ldg4_cg(inp + tid * 4);
            *(float4*)(lds_inp + tid * 4) = v;
        }
        __syncthreads();
        DOT2(wA0, wB0, 1, lds_inp, 4, lds_hpf, bA0, bB0, 0)

        // ---- phase B: layer 1 (ff: h_new0 fresh, rec: lds_hpf[1]) ----
        if (tid < 256) {
            float4 v = ldg4_cg(h_new + tid * 4);
            *(float4*)(lds_fresh + tid * 4) = v;
        }
        __syncthreads();
        DOT2(wA1, wB1, 4, lds_fresh, 4, lds_hpf + H, bA1, bB1, 1)

        // ---- phase C: layer 2 (ff: h_new1 fresh, rec: lds_hpf[2]) ----
        if (tid < 256) {
            float4 v = ldg4_cg(h_new + H + tid * 4);
            *(float4*)(lds_fresh + tid * 4) = v;
        }
        __syncthreads();
        DOT2(wA2, wB2, 4, lds_fresh, 4, lds_hpf + 2 * H, bA2, bB2, 2)

        // ---- phase D: pre-stage next step's h_old + parallel fc ----
        {
            float4 va = ldg4_issue(h_new + tid * 4);
            float4 vb = {0.f, 0.f, 0.f, 0.f};
            if (tid < 256) vb = ldg4_issue(h_new + 2048 + tid * 4);
            vm_wait();
            *(float4*)(lds_hpf + tid * 4) = va;
            if (tid < 256) *(float4*)(lds_hpf + 2048 + tid * 4) = vb;
        }
        __syncthreads();
        {
            float2 pv = *(const float2*)(lds_hpf + 2 * H + 2 * tid);
            float2 fw = *(const float2*)(lds_fc + 2 * tid);
            float a = pv.x * fw.x + pv.y * fw.y;
            a = waveReduce(a);
            if (lane == 0) red[w] = a;
        }
        __syncthreads();
        if (tid == 0) {
            float sfc = red[0] + red[1] + red[2] + red[3]
                      + red[4] + red[5] + red[6] + red[7];
            float gv = sigf(sfc + bfc_b);
            int sp1 = s + 1;
            float xv = x[(size_t)b * L + ((sp1 < L) ? sp1 : 0)];
            float nxt = (sp1 < L) ? xv : gv;
            stg_cg(&inp[b], nxt);
            out[(size_t)b * T + sp1] = nxt;
        }
        ++ph; gbar(flags, gen, ph);
    }
#undef DOT2
}

extern "C" void kernel_launch(void* const* d_in, const int* in_sizes, int n_in,
                              void* d_out, int out_size, void* d_ws, size_t ws_size,
                              hipStream_t stream) {
    const float* x    = (const float*)d_in[0];
    const float* h0   = (const float*)d_in[1];
    const float* c0   = (const float*)d_in[2];
    const float* Wih0 = (const float*)d_in[3];
    const float* Whh0 = (const float*)d_in[4];
    const float* Wih1 = (const float*)d_in[5];
    const float* Whh1 = (const float*)d_in[6];
    const float* Wih2 = (const float*)d_in[7];
    const float* Whh2 = (const float*)d_in[8];
    const float* bih  = (const float*)d_in[9];
    const float* bhh  = (const float*)d_in[10];
    const float* Wfc  = (const float*)d_in[11];
    const float* bfc  = (const float*)d_in[12];

    float* out = (float*)d_out;
    float* ws  = (float*)d_ws;

    int T = out_size / D;        // 2048
    int L = in_sizes[0] / D;     // 64

    bar_init<<<1, 512, 0, stream>>>((unsigned*)d_ws);

    void* args[] = { &x, &h0, &c0, &Wih0, &Whh0, &Wih1, &Whh1, &Wih2, &Whh2,
                     &bih, &bhh, &Wfc, &bfc, &out, &ws, &T, &L };

    (void)hipLaunchCooperativeKernel((void*)rnn_reg4, dim3(NB), dim3(NT), args, 0, stream);
}